// Round 13
// baseline (54.974 us; speedup 1.0000x reference)
//
#include <hip/hip_runtime.h>

#define D_   256
#define R_   128
#define NROW 4096            // B*K
#define TOPK 12
#define ROWS 8               // rows per main block
#define NBLK_MAIN (NROW / ROWS)   // 512
#define INVSQRT2 0.70710678f

// erf(u) ~ u * poly(u^2), deg-7 odd, fitted on [0,1.45] (|err|<~3e-4).
__device__ __forceinline__ float erf_poly(float u) {
    float uc = fminf(fmaxf(u, -1.45f), 1.45f);
    float s  = uc * uc;
    float p  = fmaf(-0.012416f, s, 0.096233f);
    p = fmaf(p, s, -0.368966f);
    p = fmaf(p, s, 1.1276018f);
    return uc * p;
}

// K1: hrT[f][r] = receptors[r,:] @ W1bot[:,f] + b1[f]  (tiny: 16.8 MFLOP)
// 4 independent fma chains; receptors row broadcast via float4.
__global__ __launch_bounds__(256) void hr_kernel(
    const float* __restrict__ receptors, const float* __restrict__ W1,
    const float* __restrict__ b1, float* __restrict__ hrT)
{
    const int r = blockIdx.x;      // 0..127
    const int f = threadIdx.x;     // 0..255
    const float* wb = W1 + D_ * D_;
    float a0 = 0.f, a1 = 0.f, a2 = 0.f, a3 = 0.f;
    #pragma unroll 4
    for (int d = 0; d < D_; d += 4) {
        float4 rv = *(const float4*)(receptors + r * D_ + d);   // broadcast
        a0 = fmaf(rv.x, wb[(d + 0) * D_ + f], a0);              // coalesced
        a1 = fmaf(rv.y, wb[(d + 1) * D_ + f], a1);
        a2 = fmaf(rv.z, wb[(d + 2) * D_ + f], a2);
        a3 = fmaf(rv.w, wb[(d + 3) * D_ + f], a3);
    }
    hrT[f * R_ + r] = (a0 + a1) + (a2 + a3) + b1[f];
}

// K2: mega-fused main. One block = 8 rows, 512 threads (8 waves).
// In-block hk GEMM (keys LDS-staged, W1 rows coalesced from L2) ->
// gelu' -> gkl in LDS (never HBM) -> affinity -> top-k/softmax -> bound/RMS.
__global__ __launch_bounds__(512, 4) void main_kernel(
    const float* __restrict__ keys, const float* __restrict__ receptors,
    const float* __restrict__ W1,   const float* __restrict__ W2,
    const float* __restrict__ b2p,  const float* __restrict__ scalep,
    const float* __restrict__ hrT,
    float* __restrict__ out, float* __restrict__ partials)
{
    __shared__ float keys_lds[ROWS][D_];    // 8 KB (alive through phase F)
    __shared__ float gkl[ROWS * D_];        // 8 KB [row][f]
    __shared__ float part_f[8][ROWS][R_];   // 32 KB [fblock][row][r]
    __shared__ float bind_lds[ROWS][R_];    // 4 KB
    __shared__ float c0row[ROWS];
    __shared__ float redS[ROWS], redN[ROWS];
    __shared__ float redX[ROWS][4];
    __shared__ float redV[2][8];

    const int t    = threadIdx.x;
    const int blk  = blockIdx.x;
    const int rowg = blk * ROWS;
    const int lane = t & 63;
    const int w    = t >> 6;          // wave 0..7

    // stage keys rows (8 x 256 f32 = 512 float4: one per thread)
    ((float4*)keys_lds)[t] = ((const float4*)(keys + rowg * D_))[t];
    __syncthreads();

    // ---- hk GEMM in-block: wave w = row w; lane -> cols c4..c4+3 ----
    // keys_lds float4 reads are wave-uniform broadcasts; W1 row reads are
    // fully coalesced (64 lanes x 16B = the whole 1KB row); W1 is L2-hot.
    const int c4 = lane * 4;
    float hk[4] = {};
    #pragma unroll 2
    for (int k0 = 0; k0 < D_; k0 += 4) {
        float4 kv  = *(const float4*)&keys_lds[w][k0];
        float4 w0v = *(const float4*)(W1 + (k0 + 0) * D_ + c4);
        float4 w1v = *(const float4*)(W1 + (k0 + 1) * D_ + c4);
        float4 w2v = *(const float4*)(W1 + (k0 + 2) * D_ + c4);
        float4 w3v = *(const float4*)(W1 + (k0 + 3) * D_ + c4);
        hk[0] = fmaf(kv.x, w0v.x, hk[0]); hk[1] = fmaf(kv.x, w0v.y, hk[1]);
        hk[2] = fmaf(kv.x, w0v.z, hk[2]); hk[3] = fmaf(kv.x, w0v.w, hk[3]);
        hk[0] = fmaf(kv.y, w1v.x, hk[0]); hk[1] = fmaf(kv.y, w1v.y, hk[1]);
        hk[2] = fmaf(kv.y, w1v.z, hk[2]); hk[3] = fmaf(kv.y, w1v.w, hk[3]);
        hk[0] = fmaf(kv.z, w2v.x, hk[0]); hk[1] = fmaf(kv.z, w2v.y, hk[1]);
        hk[2] = fmaf(kv.z, w2v.z, hk[2]); hk[3] = fmaf(kv.z, w2v.w, hk[3]);
        hk[0] = fmaf(kv.w, w3v.x, hk[0]); hk[1] = fmaf(kv.w, w3v.y, hk[1]);
        hk[2] = fmaf(kv.w, w3v.z, hk[2]); hk[3] = fmaf(kv.w, w3v.w, hk[3]);
    }

    // ---- gelu epilogue: gk = W2*gelu'(hk) -> LDS; c0 = sum W2*gelu(hk) ----
    {
        float4 wv = *(const float4*)(W2 + c4);
        const float wa[4] = { wv.x, wv.y, wv.z, wv.w };
        float g[4];
        float cs = 0.f;
        #pragma unroll
        for (int j = 0; j < 4; ++j) {
            float xx  = hk[j];
            float er  = erf_poly(xx * INVSQRT2);
            float Phi = fmaf(0.5f, er, 0.5f);                  // CDF
            float phi = 0.39894228f * __expf(-0.5f * xx * xx); // pdf
            g[j] = wa[j] * fmaf(xx, phi, Phi);                 // W2*gelu'
            cs   = fmaf(wa[j], xx * Phi, cs);                  // W2*gelu
        }
        *(float4*)&gkl[w * D_ + c4] = make_float4(g[0], g[1], g[2], g[3]);
        #pragma unroll
        for (int o = 32; o > 0; o >>= 1) cs += __shfl_xor(cs, o, 64);
        if (lane == 0) c0row[w] = cs + b2p[0];
    }
    __syncthreads();

    // ---- Phase B': affinity partials = gk . hrT over f-block w (32 f's) ----
    const int r2 = 2 * lane;
    float acc[ROWS][2] = {};
    const float* hb = hrT + (w * 32) * R_ + r2;
    #pragma unroll 2
    for (int j4 = 0; j4 < 8; ++j4) {
        const int f0 = w * 32 + j4 * 4;
        float2 h0 = *(const float2*)(hb + (j4 * 4 + 0) * R_);
        float2 h1 = *(const float2*)(hb + (j4 * 4 + 1) * R_);
        float2 h2 = *(const float2*)(hb + (j4 * 4 + 2) * R_);
        float2 h3 = *(const float2*)(hb + (j4 * 4 + 3) * R_);
        #pragma unroll
        for (int row = 0; row < ROWS; ++row) {
            float4 g = *(const float4*)&gkl[row * D_ + f0];
            acc[row][0] = fmaf(g.x, h0.x, acc[row][0]);
            acc[row][1] = fmaf(g.x, h0.y, acc[row][1]);
            acc[row][0] = fmaf(g.y, h1.x, acc[row][0]);
            acc[row][1] = fmaf(g.y, h1.y, acc[row][1]);
            acc[row][0] = fmaf(g.z, h2.x, acc[row][0]);
            acc[row][1] = fmaf(g.z, h2.y, acc[row][1]);
            acc[row][0] = fmaf(g.w, h3.x, acc[row][0]);
            acc[row][1] = fmaf(g.w, h3.y, acc[row][1]);
        }
    }
    #pragma unroll
    for (int row = 0; row < ROWS; ++row)
        *(float2*)&part_f[w][row][r2] = make_float2(acc[row][0], acc[row][1]);
    __syncthreads();

    // ---- Phase C/D: wave w owns row w; combine 8 f-blocks; bisection
    //      top-12; in-wave softmax + stats ----
    {
        float sx = 0.f, sy = 0.f;
        #pragma unroll
        for (int fb = 0; fb < 8; ++fb) {
            float2 p = *(const float2*)&part_f[fb][w][r2];
            sx += p.x; sy += p.y;
        }
        const float c0v = c0row[w];
        float a0 = sx + c0v;
        float a1 = sy + c0v;

        float mx = fmaxf(a0, a1), mn = fminf(a0, a1);
        #pragma unroll
        for (int o = 32; o > 0; o >>= 1) {
            mx = fmaxf(mx, __shfl_xor(mx, o, 64));
            mn = fminf(mn, __shfl_xor(mn, o, 64));
        }
        float lo = mn - 1e-3f, hi = mx + 1e-3f;
        for (int it = 0; it < 16; ++it) {
            float mid = 0.5f * (lo + hi);
            int c = __popcll(__ballot(a0 > mid)) + __popcll(__ballot(a1 > mid));
            if (c >= TOPK) lo = mid; else hi = mid;
        }
        const float thr = lo;

        float e0 = __expf(a0 - mx), e1 = __expf(a1 - mx);
        float s = e0 + e1;
        #pragma unroll
        for (int o = 32; o > 0; o >>= 1) s += __shfl_xor(s, o, 64);
        const float inv_den = 1.0f / s;
        const float sg0 = 1.0f / (1.0f + __expf(-10.0f * (a0 - thr)));
        const float sg1 = 1.0f / (1.0f + __expf(-10.0f * (a1 - thr)));
        const float b0  = e0 * inv_den * sg0;
        const float b1v = e1 * inv_den * sg1;
        *(float2*)&bind_lds[w][r2] = make_float2(b0, b1v);
        float q = b0 * b0 + b1v * b1v;
        float n = b0 * __logf(b0 + 1e-8f) + b1v * __logf(b1v + 1e-8f);
        #pragma unroll
        for (int o = 32; o > 0; o >>= 1) {
            q += __shfl_xor(q, o, 64);
            n += __shfl_xor(n, o, 64);
        }
        if (lane == 0) { redS[w] = q; redN[w] = n; }
    }
    __syncthreads();

    if (t == 0) {
        float sb = 0.f, se = 0.f;
        #pragma unroll
        for (int i = 0; i < ROWS; i++) { sb += redS[i]; se += redN[i]; }
        partials[blk * 4 + 0] = sb;
        partials[blk * 4 + 1] = se;
    }

    // ---- Phase F: bound = binding @ receptors; keys from LDS; RMS-norm ----
    const int d     = t & 255;
    const int rh    = t >> 8;
    const int rbase = rh * 4;
    float bnd[4] = {};
    #pragma unroll 2
    for (int rr = 0; rr < R_; rr += 4) {
        float rc0 = receptors[(rr + 0) * D_ + d];
        float rc1 = receptors[(rr + 1) * D_ + d];
        float rc2 = receptors[(rr + 2) * D_ + d];
        float rc3 = receptors[(rr + 3) * D_ + d];
        #pragma unroll
        for (int i = 0; i < 4; ++i) {
            float4 v = *(const float4*)&bind_lds[rbase + i][rr];
            bnd[i] = fmaf(rc0, v.x, fmaf(rc1, v.y, fmaf(rc2, v.z, fmaf(rc3, v.w, bnd[i]))));
        }
    }
    float x[4], xs[4];
    #pragma unroll
    for (int i = 0; i < 4; ++i) {
        x[i]  = keys_lds[rbase + i][d] + bnd[i];
        xs[i] = x[i] * x[i];
    }
    #pragma unroll
    for (int o = 32; o > 0; o >>= 1) {
        xs[0] += __shfl_xor(xs[0], o, 64);
        xs[1] += __shfl_xor(xs[1], o, 64);
        xs[2] += __shfl_xor(xs[2], o, 64);
        xs[3] += __shfl_xor(xs[3], o, 64);
    }
    if (lane == 0) {
        #pragma unroll
        for (int i = 0; i < 4; ++i) redX[rbase + i][w & 3] = xs[i];
    }
    __syncthreads();
    const float scl = scalep[0];
    float vs = 0.f, vq = 0.f;
    #pragma unroll
    for (int i = 0; i < 4; ++i) {
        const int row = rbase + i;
        float ms = (redX[row][0] + redX[row][1] + redX[row][2] + redX[row][3]) * (1.0f / D_);
        float rs = scl * rsqrtf(ms + 1e-8f);
        float st = x[i] * rs;
        out[(rowg + row) * D_ + d] = st;
        vs += st; vq += st * st;
    }
    #pragma unroll
    for (int o = 32; o > 0; o >>= 1) {
        vs += __shfl_xor(vs, o, 64);
        vq += __shfl_xor(vq, o, 64);
    }
    if (lane == 0) { redV[0][w] = vs; redV[1][w] = vq; }
    __syncthreads();
    if (t == 0) {
        float v2s = 0.f, v2q = 0.f;
        #pragma unroll
        for (int i = 0; i < 8; i++) { v2s += redV[0][i]; v2q += redV[1][i]; }
        partials[blk * 4 + 2] = v2s;
        partials[blk * 4 + 3] = v2q;
    }
}

// K3: deterministic reduction of per-block partials -> 3 scalars
__global__ __launch_bounds__(256) void finalize(
    const float* __restrict__ partials, float* __restrict__ out)
{
    __shared__ float sh[4][4];
    const int t = threadIdx.x;
    float s0 = 0.f, s1 = 0.f, s2 = 0.f, s3 = 0.f;
    for (int k = t; k < NBLK_MAIN; k += 256) {
        float4 p = *(const float4*)&partials[k * 4];
        s0 += p.x; s1 += p.y; s2 += p.z; s3 += p.w;
    }
    #pragma unroll
    for (int o = 32; o > 0; o >>= 1) {
        s0 += __shfl_xor(s0, o, 64);
        s1 += __shfl_xor(s1, o, 64);
        s2 += __shfl_xor(s2, o, 64);
        s3 += __shfl_xor(s3, o, 64);
    }
    const int w = t >> 6, lane = t & 63;
    if (lane == 0) { sh[0][w] = s0; sh[1][w] = s1; sh[2][w] = s2; sh[3][w] = s3; }
    __syncthreads();
    if (t == 0) {
        float S0 = sh[0][0] + sh[0][1] + sh[0][2] + sh[0][3];
        float S1 = sh[1][0] + sh[1][1] + sh[1][2] + sh[1][3];
        float S2 = sh[2][0] + sh[2][1] + sh[2][2] + sh[2][3];
        float S3 = sh[3][0] + sh[3][1] + sh[3][2] + sh[3][3];
        const float N = (float)(NROW * D_);
        out[NROW * D_ + 0] = S0 / (float)NROW;
        out[NROW * D_ + 1] = -S1 / (float)NROW;
        out[NROW * D_ + 2] = (S3 - S2 * S2 / N) / (N - 1.0f);
    }
}

extern "C" void kernel_launch(void* const* d_in, const int* in_sizes, int n_in,
                              void* d_out, int out_size, void* d_ws, size_t ws_size,
                              hipStream_t stream) {
    const float* keys      = (const float*)d_in[0];
    const float* receptors = (const float*)d_in[1];
    const float* W1        = (const float*)d_in[2];
    const float* b1        = (const float*)d_in[3];
    const float* W2        = (const float*)d_in[4];
    const float* b2        = (const float*)d_in[5];
    const float* oscale    = (const float*)d_in[6];
    float* out = (float*)d_out;
    char* ws   = (char*)d_ws;

    float* hrT      = (float*)ws;                      // 128 KB
    float* partials = (float*)(ws + 131072);           // 8 KB

    hr_kernel<<<dim3(R_), dim3(D_), 0, stream>>>(receptors, W1, b1, hrT);
    main_kernel<<<dim3(NBLK_MAIN), dim3(512), 0, stream>>>(
        keys, receptors, W1, W2, b2, oscale, hrT, out, partials);
    finalize<<<dim3(1), dim3(256), 0, stream>>>(partials, out);
}

// Round 14
// 38.828 us; speedup vs baseline: 1.4158x; 1.4158x over previous
//
#include <hip/hip_runtime.h>

#define D_   256
#define R_   128
#define NROW 4096            // B*K
#define TOPK 12
#define ROWS 8               // rows per main block
#define NBLK_MAIN (NROW / ROWS)   // 512
#define INVSQRT2 0.70710678f

// erf(u) ~ u * poly(u^2), deg-7 odd, fitted on [0,1.45] (|err|<~3e-4).
__device__ __forceinline__ float erf_poly(float u) {
    float uc = fminf(fmaxf(u, -1.45f), 1.45f);
    float s  = uc * uc;
    float p  = fmaf(-0.012416f, s, 0.096233f);
    p = fmaf(p, s, -0.368966f);
    p = fmaf(p, s, 1.1276018f);
    return uc * p;
}

// K1: blocks 0..255 = hk GEMM (64x64 tile, 512 threads: same tile/traffic as
//     R9 but 2 waves/SIMD for latency hiding) + gelu epilogue;
//     blocks 256..319 = hr rows (2 per block).
//   gk    [bk][f]  f32 = W2[f] * gelu'(hk[bk][f])
//   c0part[bk][4]  f32 = per-column-quarter partial of sum_f W2[f]*gelu(hk)
//   hrT   [f][r]   f32 = receptors@W1bot + b1 (transposed)
__global__ __launch_bounds__(512) void prep_kernel(
    const float* __restrict__ keys, const float* __restrict__ receptors,
    const float* __restrict__ W1,   const float* __restrict__ b1,
    const float* __restrict__ W2,
    float* __restrict__ gk, float* __restrict__ c0part,
    float* __restrict__ hrT)
{
    __shared__ float At[16][64];
    __shared__ float Bs[16][64];
    const int blk = blockIdx.x;
    const int t   = threadIdx.x;

    if (blk < 256) {
        const int bx = blk & 3;
        const int by = blk >> 2;
        // compute mapping: 4 rows x ... -> thread owns rows ty*2..+1, cols tx*4..+3
        const int tx = t & 15, ty = t >> 4;       // ty 0..31
        // loader mapping: threads 0..255 load A exactly as R9; 256..511 load B.
        const int arow = t >> 2, akq = t & 3;             // valid for t<256
        const int bkr  = (t - 256) >> 4, bnc = (t - 256) & 15;  // t>=256
        const float* Aptr = keys + (by * 64 + arow) * D_;
        const int bcol = bx * 64 + bnc * 4;

        float acc[2][4] = {};
        float4 pre;
        if (t < 256) pre = *(const float4*)(Aptr + akq * 4);
        else         pre = *(const float4*)(W1 + bkr * D_ + bcol);
        for (int k0 = 0; k0 < 256; k0 += 16) {
            __syncthreads();
            if (t < 256) {
                At[akq * 4 + 0][arow] = pre.x;
                At[akq * 4 + 1][arow] = pre.y;
                At[akq * 4 + 2][arow] = pre.z;
                At[akq * 4 + 3][arow] = pre.w;
            } else {
                *(float4*)&Bs[bkr][bnc * 4] = pre;
            }
            __syncthreads();
            if (k0 + 16 < 256) {
                if (t < 256) pre = *(const float4*)(Aptr + k0 + 16 + akq * 4);
                else         pre = *(const float4*)(W1 + (k0 + 16 + bkr) * D_ + bcol);
            }
            #pragma unroll
            for (int kk = 0; kk < 16; kk++) {
                float2 a2 = *(const float2*)&At[kk][ty * 2];
                float4 b4 = *(const float4*)&Bs[kk][tx * 4];
                acc[0][0] = fmaf(a2.x, b4.x, acc[0][0]);
                acc[0][1] = fmaf(a2.x, b4.y, acc[0][1]);
                acc[0][2] = fmaf(a2.x, b4.z, acc[0][2]);
                acc[0][3] = fmaf(a2.x, b4.w, acc[0][3]);
                acc[1][0] = fmaf(a2.y, b4.x, acc[1][0]);
                acc[1][1] = fmaf(a2.y, b4.y, acc[1][1]);
                acc[1][2] = fmaf(a2.y, b4.z, acc[1][2]);
                acc[1][3] = fmaf(a2.y, b4.w, acc[1][3]);
            }
        }
        // ---- epilogue: gk = W2*gelu'(hk); c0part = per-quarter sum W2*gelu ----
        const int colb = bx * 64 + tx * 4;
        const float4 w2v = *(const float4*)(W2 + colb);
        const float w2a[4] = { w2v.x, w2v.y, w2v.z, w2v.w };
        #pragma unroll
        for (int i = 0; i < 2; i++) {
            float g4[4];
            float cs = 0.f;
            #pragma unroll
            for (int j = 0; j < 4; j++) {
                float x  = acc[i][j];
                float er = erf_poly(x * INVSQRT2);
                float Phi = fmaf(0.5f, er, 0.5f);                  // CDF
                float phi = 0.39894228f * __expf(-0.5f * x * x);   // pdf
                float gp  = fmaf(x, phi, Phi);                     // gelu'
                g4[j] = w2a[j] * gp;
                cs = fmaf(w2a[j], x * Phi, cs);                    // W2*gelu
            }
            const int rowi = by * 64 + ty * 2 + i;
            *(float4*)(gk + rowi * D_ + colb) = make_float4(g4[0], g4[1], g4[2], g4[3]);
            cs += __shfl_xor(cs, 1, 64);
            cs += __shfl_xor(cs, 2, 64);
            cs += __shfl_xor(cs, 4, 64);
            cs += __shfl_xor(cs, 8, 64);
            if (tx == 0) c0part[rowi * 4 + bx] = cs;
        }
    } else {
        // ---- hr rows, transposed (f32); 2 rows per block ----
        const int r = (blk - 256) * 2 + (t >> 8);   // 0..127
        const int f = t & 255;
        const float* wb = W1 + D_ * D_;
        float a0 = 0.f, a1 = 0.f, a2 = 0.f, a3 = 0.f;
        #pragma unroll 4
        for (int d = 0; d < D_; d += 4) {
            float4 rv = *(const float4*)(receptors + r * D_ + d);
            a0 = fmaf(rv.x, wb[(d + 0) * D_ + f], a0);
            a1 = fmaf(rv.y, wb[(d + 1) * D_ + f], a1);
            a2 = fmaf(rv.z, wb[(d + 2) * D_ + f], a2);
            a3 = fmaf(rv.w, wb[(d + 3) * D_ + f], a3);
        }
        hrT[f * R_ + r] = (a0 + a1) + (a2 + a3) + b1[f];
    }
}

// K2: fused main kernel. One block = 8 rows, 512 threads (8 waves).
// R9's proven phases at ROWS=8: halves per-launch hrT/receptors L2 traffic.
__global__ __launch_bounds__(512, 4) void main_kernel(
    const float* __restrict__ keys, const float* __restrict__ receptors,
    const float* __restrict__ b2p,  const float* __restrict__ scalep,
    const float* __restrict__ gk,   const float* __restrict__ c0part,
    const float* __restrict__ hrT,
    float* __restrict__ out, float* __restrict__ partials)
{
    __shared__ float gkl[ROWS * D_];        // 8 KB [row][f]
    __shared__ float part_f[8][ROWS][R_];   // 32 KB [fblock][row][r]
    __shared__ float bind_lds[ROWS][R_];    // 4 KB
    __shared__ float c0row[ROWS];
    __shared__ float redS[ROWS], redN[ROWS];
    __shared__ float redX[ROWS][4];
    __shared__ float redV[2][8];

    const int t    = threadIdx.x;
    const int blk  = blockIdx.x;
    const int rowg = blk * ROWS;
    const int lane = t & 63;
    const int w    = t >> 6;          // wave 0..7

    // stage gk rows (8 x 256 f32 = 512 float4: one per thread) + c0row
    ((float4*)gkl)[t] = ((const float4*)(gk + rowg * D_))[t];
    if (t < ROWS) {
        float4 cp = *(const float4*)(c0part + (rowg + t) * 4);
        c0row[t] = cp.x + cp.y + cp.z + cp.w + b2p[0];
    }
    __syncthreads();

    // ---- Phase B': affinity partials = gk . hrT over f-block w (32 f's) ----
    // lane -> r pair; coalesced float2 hrT loads; gkl float4 broadcasts.
    const int r2 = 2 * lane;
    float acc[ROWS][2] = {};
    const float* hb = hrT + (w * 32) * R_ + r2;
    #pragma unroll 2
    for (int j4 = 0; j4 < 8; ++j4) {
        const int f0 = w * 32 + j4 * 4;
        float2 h0 = *(const float2*)(hb + (j4 * 4 + 0) * R_);
        float2 h1 = *(const float2*)(hb + (j4 * 4 + 1) * R_);
        float2 h2 = *(const float2*)(hb + (j4 * 4 + 2) * R_);
        float2 h3 = *(const float2*)(hb + (j4 * 4 + 3) * R_);
        #pragma unroll
        for (int row = 0; row < ROWS; ++row) {
            float4 g = *(const float4*)&gkl[row * D_ + f0];
            acc[row][0] = fmaf(g.x, h0.x, acc[row][0]);
            acc[row][1] = fmaf(g.x, h0.y, acc[row][1]);
            acc[row][0] = fmaf(g.y, h1.x, acc[row][0]);
            acc[row][1] = fmaf(g.y, h1.y, acc[row][1]);
            acc[row][0] = fmaf(g.z, h2.x, acc[row][0]);
            acc[row][1] = fmaf(g.z, h2.y, acc[row][1]);
            acc[row][0] = fmaf(g.w, h3.x, acc[row][0]);
            acc[row][1] = fmaf(g.w, h3.y, acc[row][1]);
        }
    }
    #pragma unroll
    for (int row = 0; row < ROWS; ++row)
        *(float2*)&part_f[w][row][r2] = make_float2(acc[row][0], acc[row][1]);
    __syncthreads();

    // ---- Phase C/D: wave w owns row w; combine 8 f-blocks; bisection
    //      top-12; in-wave softmax + stats ----
    {
        float sx = 0.f, sy = 0.f;
        #pragma unroll
        for (int fb = 0; fb < 8; ++fb) {
            float2 p = *(const float2*)&part_f[fb][w][r2];
            sx += p.x; sy += p.y;
        }
        const float c0v = c0row[w];
        float a0 = sx + c0v;
        float a1 = sy + c0v;

        float mx = fmaxf(a0, a1), mn = fminf(a0, a1);
        #pragma unroll
        for (int o = 32; o > 0; o >>= 1) {
            mx = fmaxf(mx, __shfl_xor(mx, o, 64));
            mn = fminf(mn, __shfl_xor(mn, o, 64));
        }
        float lo = mn - 1e-3f, hi = mx + 1e-3f;
        for (int it = 0; it < 16; ++it) {
            float mid = 0.5f * (lo + hi);
            int c = __popcll(__ballot(a0 > mid)) + __popcll(__ballot(a1 > mid));
            if (c >= TOPK) lo = mid; else hi = mid;
        }
        const float thr = lo;

        float e0 = __expf(a0 - mx), e1 = __expf(a1 - mx);
        float s = e0 + e1;
        #pragma unroll
        for (int o = 32; o > 0; o >>= 1) s += __shfl_xor(s, o, 64);
        const float inv_den = 1.0f / s;
        const float sg0 = 1.0f / (1.0f + __expf(-10.0f * (a0 - thr)));
        const float sg1 = 1.0f / (1.0f + __expf(-10.0f * (a1 - thr)));
        const float b0  = e0 * inv_den * sg0;
        const float b1v = e1 * inv_den * sg1;
        *(float2*)&bind_lds[w][r2] = make_float2(b0, b1v);
        float q = b0 * b0 + b1v * b1v;
        float n = b0 * __logf(b0 + 1e-8f) + b1v * __logf(b1v + 1e-8f);
        #pragma unroll
        for (int o = 32; o > 0; o >>= 1) {
            q += __shfl_xor(q, o, 64);
            n += __shfl_xor(n, o, 64);
        }
        if (lane == 0) { redS[w] = q; redN[w] = n; }
    }
    __syncthreads();

    if (t == 0) {
        float sb = 0.f, se = 0.f;
        #pragma unroll
        for (int i = 0; i < ROWS; i++) { sb += redS[i]; se += redN[i]; }
        partials[blk * 4 + 0] = sb;
        partials[blk * 4 + 1] = se;
    }

    // ---- Phase F: bound = binding @ receptors ([r][d] coalesced scalar
    //      loads, bind_lds float4 broadcasts); RMS-norm; var partials ----
    const int d     = t & 255;
    const int rh    = t >> 8;
    const int rbase = rh * 4;
    float bnd[4] = {};
    #pragma unroll 2
    for (int rr = 0; rr < R_; rr += 4) {
        float rc0 = receptors[(rr + 0) * D_ + d];
        float rc1 = receptors[(rr + 1) * D_ + d];
        float rc2 = receptors[(rr + 2) * D_ + d];
        float rc3 = receptors[(rr + 3) * D_ + d];
        #pragma unroll
        for (int i = 0; i < 4; ++i) {
            float4 v = *(const float4*)&bind_lds[rbase + i][rr];
            bnd[i] = fmaf(rc0, v.x, fmaf(rc1, v.y, fmaf(rc2, v.z, fmaf(rc3, v.w, bnd[i]))));
        }
    }
    float x[4], xs[4];
    #pragma unroll
    for (int i = 0; i < 4; ++i) {
        x[i]  = keys[(rowg + rbase + i) * D_ + d] + bnd[i];
        xs[i] = x[i] * x[i];
    }
    #pragma unroll
    for (int o = 32; o > 0; o >>= 1) {
        xs[0] += __shfl_xor(xs[0], o, 64);
        xs[1] += __shfl_xor(xs[1], o, 64);
        xs[2] += __shfl_xor(xs[2], o, 64);
        xs[3] += __shfl_xor(xs[3], o, 64);
    }
    if (lane == 0) {
        #pragma unroll
        for (int i = 0; i < 4; ++i) redX[rbase + i][w & 3] = xs[i];
    }
    __syncthreads();
    const float scl = scalep[0];
    float vs = 0.f, vq = 0.f;
    #pragma unroll
    for (int i = 0; i < 4; ++i) {
        const int row = rbase + i;
        float ms = (redX[row][0] + redX[row][1] + redX[row][2] + redX[row][3]) * (1.0f / D_);
        float rs = scl * rsqrtf(ms + 1e-8f);
        float st = x[i] * rs;
        out[(rowg + row) * D_ + d] = st;
        vs += st; vq += st * st;
    }
    #pragma unroll
    for (int o = 32; o > 0; o >>= 1) {
        vs += __shfl_xor(vs, o, 64);
        vq += __shfl_xor(vq, o, 64);
    }
    if (lane == 0) { redV[0][w] = vs; redV[1][w] = vq; }
    __syncthreads();
    if (t == 0) {
        float v2s = 0.f, v2q = 0.f;
        #pragma unroll
        for (int i = 0; i < 8; i++) { v2s += redV[0][i]; v2q += redV[1][i]; }
        partials[blk * 4 + 2] = v2s;
        partials[blk * 4 + 3] = v2q;
    }
}

// K3: deterministic reduction of per-block partials -> 3 scalars
__global__ __launch_bounds__(256) void finalize(
    const float* __restrict__ partials, float* __restrict__ out)
{
    __shared__ float sh[4][4];
    const int t = threadIdx.x;
    float s0 = 0.f, s1 = 0.f, s2 = 0.f, s3 = 0.f;
    for (int k = t; k < NBLK_MAIN; k += 256) {
        float4 p = *(const float4*)&partials[k * 4];
        s0 += p.x; s1 += p.y; s2 += p.z; s3 += p.w;
    }
    #pragma unroll
    for (int o = 32; o > 0; o >>= 1) {
        s0 += __shfl_xor(s0, o, 64);
        s1 += __shfl_xor(s1, o, 64);
        s2 += __shfl_xor(s2, o, 64);
        s3 += __shfl_xor(s3, o, 64);
    }
    const int w = t >> 6, lane = t & 63;
    if (lane == 0) { sh[0][w] = s0; sh[1][w] = s1; sh[2][w] = s2; sh[3][w] = s3; }
    __syncthreads();
    if (t == 0) {
        float S0 = sh[0][0] + sh[0][1] + sh[0][2] + sh[0][3];
        float S1 = sh[1][0] + sh[1][1] + sh[1][2] + sh[1][3];
        float S2 = sh[2][0] + sh[2][1] + sh[2][2] + sh[2][3];
        float S3 = sh[3][0] + sh[3][1] + sh[3][2] + sh[3][3];
        const float N = (float)(NROW * D_);
        out[NROW * D_ + 0] = S0 / (float)NROW;
        out[NROW * D_ + 1] = -S1 / (float)NROW;
        out[NROW * D_ + 2] = (S3 - S2 * S2 / N) / (N - 1.0f);
    }
}

extern "C" void kernel_launch(void* const* d_in, const int* in_sizes, int n_in,
                              void* d_out, int out_size, void* d_ws, size_t ws_size,
                              hipStream_t stream) {
    const float* keys      = (const float*)d_in[0];
    const float* receptors = (const float*)d_in[1];
    const float* W1        = (const float*)d_in[2];
    const float* b1        = (const float*)d_in[3];
    const float* W2        = (const float*)d_in[4];
    const float* b2        = (const float*)d_in[5];
    const float* oscale    = (const float*)d_in[6];
    float* out = (float*)d_out;
    char* ws   = (char*)d_ws;

    float* gk       = (float*)ws;                                  // 4 MB
    float* hrT      = (float*)(ws + 4194304);                      // 128 KB
    float* c0part   = (float*)(ws + 4194304 + 131072);             // 64 KB
    float* partials = (float*)(ws + 4194304 + 131072 + 65536);     // 8 KB

    prep_kernel<<<dim3(320), dim3(512), 0, stream>>>(
        keys, receptors, W1, b1, W2, gk, c0part, hrT);
    main_kernel<<<dim3(NBLK_MAIN), dim3(512), 0, stream>>>(
        keys, receptors, b2, oscale, gk, c0part, hrT, out, partials);
    finalize<<<dim3(1), dim3(256), 0, stream>>>(partials, out);
}